// Round 3
// baseline (736.777 us; speedup 1.0000x reference)
//
#include <hip/hip_runtime.h>

// ============================================================================
// MoE block (top-2 of 8 experts), T=8192 tokens, d=1024, h=2048.
// R3: R2 + explicit LDS double-buffered prefetch in both MFMA GEMMs.
// K-loop: one barrier per iteration; prefetch slab k+1 right after the
// barrier, compute slab k. Every global_load_lds gets one compute phase of
// latency hiding before its vmcnt(0) drain (R2 drained immediately).
//
// ws layout (bytes):
//   0       counts[8]
//   64      offsets[9]
//   128     cursors[8]
//   192     tileoff[9]     (128-row tile prefix per expert)
//   256     topk_idx[16384] int
//   65792   topk_gate[16384] float
//   131328  block_probsum[2048*8] float
//   196864  assign_token[16384] int
//   262400  assign_gate[16384] float
//   1 MB    Xg[(16384+128) x 1024] bf16   (33.8 MB)
//   ~34.9MB w1b[8*2048*1024] bf16         (33.6 MB)
//   ~68.4MB w2b[8*1024*2048] bf16         (33.6 MB)
//   ~102MB  Hbuf[(16384+128) x 2048] bf16 (67.6 MB)   total ~170 MB
// ============================================================================

#define TOKS 8192
#define DIMD 1024
#define HID  2048
#define NE   8

#define OFF_COUNTS   0
#define OFF_OFFSETS  64
#define OFF_CURSORS  128
#define OFF_TILEOFF  192
#define OFF_TOPKI    256
#define OFF_TOPKG    (OFF_TOPKI + TOKS*2*4)
#define OFF_BLKPS    (OFF_TOPKG + TOKS*2*4)
#define OFF_ATOK     (OFF_BLKPS + 2048*NE*4)
#define OFF_AGATE    (OFF_ATOK + TOKS*2*4)
#define OFF_XG       (1u << 20)
#define XG_ROWS      (TOKS*2 + 128)
#define OFF_W1B      (OFF_XG  + (size_t)XG_ROWS * DIMD * 2)
#define OFF_W2B      (OFF_W1B + (size_t)NE * HID * DIMD * 2)
#define OFF_H        (OFF_W2B + (size_t)NE * DIMD * HID * 2)

typedef __bf16 bf16x8 __attribute__((ext_vector_type(8)));
typedef float  floatx4 __attribute__((ext_vector_type(4)));

__device__ __forceinline__ float bf2f(unsigned short u) {
    return __uint_as_float(((unsigned)u) << 16);
}
__device__ __forceinline__ unsigned short f2bf(float f) {
    unsigned u = __float_as_uint(f);
    unsigned r = (u + 0x7FFFu + ((u >> 16) & 1u)) >> 16;
    return (unsigned short)r;
}

#define GLOBAL_AS(p) ((const __attribute__((address_space(1))) unsigned int*)(p))
#define LDS_AS(p)    ((__attribute__((address_space(3))) unsigned int*)(p))

// ---------------------------------------------------------------------------
__global__ void zero_out_kernel(float4* __restrict__ out, int n4) {
    int i = blockIdx.x * blockDim.x + threadIdx.x;
    int stride = gridDim.x * blockDim.x;
    for (; i < n4; i += stride) out[i] = make_float4(0.f, 0.f, 0.f, 0.f);
}

// ---------------------------------------------------------------------------
__global__ void convert_w_kernel(const float4* __restrict__ w,
                                 ushort4* __restrict__ wb, int n4) {
    int i = blockIdx.x * blockDim.x + threadIdx.x;
    int stride = gridDim.x * blockDim.x;
    for (; i < n4; i += stride) {
        float4 v = w[i];
        ushort4 o;
        o.x = f2bf(v.x); o.y = f2bf(v.y); o.z = f2bf(v.z); o.w = f2bf(v.w);
        wb[i] = o;
    }
}

// ---------------------------------------------------------------------------
// One wave per token: logits = x[t] . rw[e], softmax over 8, top-2, gates.
__global__ __launch_bounds__(256) void router_kernel(
    const float* __restrict__ x, const float* __restrict__ rw,
    int* __restrict__ topki, float* __restrict__ topkg,
    float* __restrict__ blkps)
{
    int wave = threadIdx.x >> 6;
    int lane = threadIdx.x & 63;
    int t = blockIdx.x * 4 + wave;
    const float* xt = x + (size_t)t * DIMD;

    float acc[NE];
#pragma unroll
    for (int e = 0; e < NE; e++) acc[e] = 0.f;
    for (int i = 0; i < DIMD / 64; i++) {
        float xv = xt[lane + 64 * i];
#pragma unroll
        for (int e = 0; e < NE; e++) acc[e] += xv * rw[e * DIMD + lane + 64 * i];
    }
#pragma unroll
    for (int off = 32; off > 0; off >>= 1) {
#pragma unroll
        for (int e = 0; e < NE; e++) acc[e] += __shfl_down(acc[e], off);
    }

    __shared__ float ps[4][NE];
    if (lane == 0) {
        float m = acc[0];
#pragma unroll
        for (int e = 1; e < NE; e++) m = fmaxf(m, acc[e]);
        float ex[NE], s = 0.f;
#pragma unroll
        for (int e = 0; e < NE; e++) { ex[e] = expf(acc[e] - m); s += ex[e]; }
        float inv = 1.f / s;
#pragma unroll
        for (int e = 0; e < NE; e++) ps[wave][e] = ex[e] * inv;

        int i0 = 0; float l0 = acc[0];
#pragma unroll
        for (int e = 1; e < NE; e++) if (acc[e] > l0) { l0 = acc[e]; i0 = e; }
        int i1 = -1; float l1 = -3.4e38f;
#pragma unroll
        for (int e = 0; e < NE; e++) if (e != i0 && acc[e] > l1) { l1 = acc[e]; i1 = e; }
        float e1 = expf(l1 - l0);
        float g0 = 1.f / (1.f + e1);
        float g1 = e1 * g0;
        topki[t * 2 + 0] = i0; topki[t * 2 + 1] = i1;
        topkg[t * 2 + 0] = g0; topkg[t * 2 + 1] = g1;
    }
    __syncthreads();
    if (threadIdx.x < NE) {
        float s = ps[0][threadIdx.x] + ps[1][threadIdx.x] + ps[2][threadIdx.x] + ps[3][threadIdx.x];
        blkps[blockIdx.x * NE + threadIdx.x] = s;
    }
}

// ---------------------------------------------------------------------------
// Single block: counts, offsets (packed row bases), cursors, 128-row tile
// prefix, aux loss.
__global__ __launch_bounds__(256) void finalize_kernel(
    const int* __restrict__ topki, const float* __restrict__ blkps,
    int* __restrict__ counts, int* __restrict__ offsets, int* __restrict__ cursors,
    int* __restrict__ tileoff, float* __restrict__ aux_out)
{
    __shared__ float psum[NE];
    __shared__ int cnt[NE];
    int tid = threadIdx.x;
    if (tid < NE) { psum[tid] = 0.f; cnt[tid] = 0; }
    __syncthreads();

    float lp[NE]; int lc[NE];
#pragma unroll
    for (int e = 0; e < NE; e++) { lp[e] = 0.f; lc[e] = 0; }
    for (int i = tid; i < 2048; i += 256) {
#pragma unroll
        for (int e = 0; e < NE; e++) lp[e] += blkps[i * NE + e];
    }
    for (int i = tid; i < TOKS * 2; i += 256) {
        int v = topki[i];
#pragma unroll
        for (int e = 0; e < NE; e++) lc[e] += (v == e) ? 1 : 0;
    }
#pragma unroll
    for (int e = 0; e < NE; e++) { atomicAdd(&psum[e], lp[e]); atomicAdd(&cnt[e], lc[e]); }
    __syncthreads();

    if (tid == 0) {
        int off = 0, to = 0;
        for (int e = 0; e < NE; e++) {
            counts[e] = cnt[e];
            offsets[e] = off; cursors[e] = off;
            tileoff[e] = to;
            off += cnt[e];
            to += (cnt[e] + 127) >> 7;
        }
        offsets[NE] = off; tileoff[NE] = to;
        float aux = 0.f;
        for (int e = 0; e < NE; e++)
            aux += ((float)cnt[e] / (float)(TOKS * 2)) * (psum[e] / (float)TOKS);
        aux_out[0] = (float)NE * aux;
    }
}

// ---------------------------------------------------------------------------
// Build packed per-expert (token, gate) lists; wave-aggregated cursor atomics.
__global__ __launch_bounds__(64) void fill_kernel(
    const int* __restrict__ topki, const float* __restrict__ topkg,
    int* __restrict__ cursors, int* __restrict__ atok, float* __restrict__ agate)
{
    int lane = threadIdx.x;
    int t = blockIdx.x * 64 + lane;
    unsigned long long below = (lane == 63) ? 0x7FFFFFFFFFFFFFFFull
                                            : ((1ull << lane) - 1ull);
#pragma unroll
    for (int k = 0; k < 2; k++) {
        int e = topki[t * 2 + k];
        float g = topkg[t * 2 + k];
        for (int ee = 0; ee < NE; ee++) {
            bool pred = (e == ee);
            unsigned long long mask = __ballot(pred ? 1 : 0);
            if (mask) {
                int leader = __ffsll((unsigned long long)mask) - 1;
                int base = 0;
                if (lane == leader) base = atomicAdd(&cursors[ee], (int)__popcll(mask));
                base = __shfl(base, leader);
                if (pred) {
                    int pos = base + (int)__popcll(mask & below);
                    atok[pos] = t;
                    agate[pos] = g;
                }
            }
        }
    }
}

// ---------------------------------------------------------------------------
// Gather x rows into packed assignment order, fp32 -> bf16.
__global__ __launch_bounds__(256) void gather_x_kernel(
    const float* __restrict__ x, const int* __restrict__ atok,
    ushort* __restrict__ Xg)
{
    int r = blockIdx.x;
    int tid = threadIdx.x;
    int tok = atok[r];
    float4 v = ((const float4*)(x + (size_t)tok * DIMD))[tid];
    ushort4 o;
    o.x = f2bf(v.x); o.y = f2bf(v.y); o.z = f2bf(v.z); o.w = f2bf(v.w);
    ((ushort4*)(Xg + (size_t)r * DIMD))[tid] = o;
}

// Prefetch one BK=32 slab of A and B into LDS buffer `buf` and advance ptrs.
#define ISSUE_SLAB(buf)                                                        \
    do {                                                                       \
        __builtin_amdgcn_global_load_lds(GLOBAL_AS(gA0),                       \
            LDS_AS(&ldsA[buf][(2 * wave) * 512]), 16, 0, 0);                   \
        __builtin_amdgcn_global_load_lds(GLOBAL_AS(gA1),                       \
            LDS_AS(&ldsA[buf][(2 * wave + 1) * 512]), 16, 0, 0);               \
        __builtin_amdgcn_global_load_lds(GLOBAL_AS(gB0),                       \
            LDS_AS(&ldsB[buf][(2 * wave) * 512]), 16, 0, 0);                   \
        __builtin_amdgcn_global_load_lds(GLOBAL_AS(gB1),                       \
            LDS_AS(&ldsB[buf][(2 * wave + 1) * 512]), 16, 0, 0);               \
        gA0 += 32; gA1 += 32; gB0 += 32; gB1 += 32;                            \
    } while (0)

// ---------------------------------------------------------------------------
// MFMA GEMM phase 1: H[r,:] = gelu(Xg[r,:] @ w1b[e]^T + b1[e]) (bf16 out).
// 128x128 tile, BK=32, 4 waves, global_load_lds width=16, double-buffered.
__global__ __launch_bounds__(256) void phase1_kernel(
    const ushort* __restrict__ Xg, const ushort* __restrict__ w1b,
    const float* __restrict__ b1,
    const int* __restrict__ counts, const int* __restrict__ offsets,
    const int* __restrict__ tileoff, unsigned short* __restrict__ Hbuf)
{
    const int NCOLT = HID / 128;   // 16
    int total = tileoff[NE] * NCOLT;
    int idx = blockIdx.x;
    if (idx >= total) return;
    int ct = idx & (NCOLT - 1);
    int rowt = idx / NCOLT;
    int e = 0;
    while (rowt >= tileoff[e + 1]) e++;
    int row0 = (rowt - tileoff[e]) * 128;
    int cnt = counts[e];
    int base = offsets[e];
    int colbase = ct * 128;

    __shared__ ushort ldsA[2][128 * 32];
    __shared__ ushort ldsB[2][128 * 32];

    int tid = threadIdx.x;
    int lane = tid & 63;
    int wave = tid >> 6;
    int wrow = wave >> 1, wcol = wave & 1;
    int l15 = lane & 15, quad = lane >> 4;

    const ushort* gA0 = Xg + (size_t)(base + row0 + 16 * (2 * wave)     + l15) * DIMD + quad * 8;
    const ushort* gA1 = Xg + (size_t)(base + row0 + 16 * (2 * wave + 1) + l15) * DIMD + quad * 8;
    const ushort* wB  = w1b + (size_t)e * HID * DIMD;
    const ushort* gB0 = wB + (size_t)(colbase + 16 * (2 * wave)     + l15) * DIMD + quad * 8;
    const ushort* gB1 = wB + (size_t)(colbase + 16 * (2 * wave + 1) + l15) * DIMD + quad * 8;

    floatx4 acc[4][4];
#pragma unroll
    for (int i = 0; i < 4; i++)
#pragma unroll
        for (int j = 0; j < 4; j++) acc[i][j] = (floatx4){0.f, 0.f, 0.f, 0.f};

    ISSUE_SLAB(0);
    const int nIter = DIMD / 32;
    for (int it = 0; it < nIter; ++it) {
        int cur = it & 1;
        __syncthreads();            // drains prefetch for buf[cur]
        if (it + 1 < nIter) ISSUE_SLAB(cur ^ 1);

        const bf16x8* fA = reinterpret_cast<const bf16x8*>(ldsA[cur]);
        const bf16x8* fB = reinterpret_cast<const bf16x8*>(ldsB[cur]);
        bf16x8 a[4], b[4];
#pragma unroll
        for (int i = 0; i < 4; i++) a[i] = fA[(4 * wrow + i) * 64 + lane];
#pragma unroll
        for (int j = 0; j < 4; j++) b[j] = fB[(4 * wcol + j) * 64 + lane];
#pragma unroll
        for (int i = 0; i < 4; i++)
#pragma unroll
            for (int j = 0; j < 4; j++)
                acc[i][j] = __builtin_amdgcn_mfma_f32_16x16x32_bf16(a[i], b[j], acc[i][j], 0, 0, 0);
    }

    // epilogue: bias + exact GELU, bf16 store. C/D: col=lane&15, row=quad*4+reg
#pragma unroll
    for (int i = 0; i < 4; i++) {
#pragma unroll
        for (int r = 0; r < 4; r++) {
            int pr = row0 + 64 * wrow + 16 * i + quad * 4 + r;
            if (pr < cnt) {
                size_t hrow = (size_t)(base + pr) * HID;
#pragma unroll
                for (int j = 0; j < 4; j++) {
                    int col = colbase + 64 * wcol + 16 * j + l15;
                    float v = acc[i][j][r] + b1[e * HID + col];
                    v = 0.5f * v * (1.f + erff(v * 0.70710678118654752f));
                    Hbuf[hrow + col] = f2bf(v);
                }
            }
        }
    }
}

// ---------------------------------------------------------------------------
// MFMA GEMM phase 2: out[tok(r),:] += gate(r)*(H[r,:] @ w2b[e]^T + b2[e]).
__global__ __launch_bounds__(256) void phase2_kernel(
    const ushort* __restrict__ Hbuf, const ushort* __restrict__ w2b,
    const float* __restrict__ b2,
    const int* __restrict__ counts, const int* __restrict__ offsets,
    const int* __restrict__ tileoff, const int* __restrict__ atok,
    const float* __restrict__ agate, float* __restrict__ out)
{
    const int NCOLT = DIMD / 128;  // 8
    int total = tileoff[NE] * NCOLT;
    int idx = blockIdx.x;
    if (idx >= total) return;
    int ct = idx & (NCOLT - 1);
    int rowt = idx / NCOLT;
    int e = 0;
    while (rowt >= tileoff[e + 1]) e++;
    int row0 = (rowt - tileoff[e]) * 128;
    int cnt = counts[e];
    int base = offsets[e];
    int colbase = ct * 128;

    __shared__ ushort ldsA[2][128 * 32];
    __shared__ ushort ldsB[2][128 * 32];

    int tid = threadIdx.x;
    int lane = tid & 63;
    int wave = tid >> 6;
    int wrow = wave >> 1, wcol = wave & 1;
    int l15 = lane & 15, quad = lane >> 4;

    const ushort* gA0 = Hbuf + (size_t)(base + row0 + 16 * (2 * wave)     + l15) * HID + quad * 8;
    const ushort* gA1 = Hbuf + (size_t)(base + row0 + 16 * (2 * wave + 1) + l15) * HID + quad * 8;
    const ushort* wB  = w2b + (size_t)e * DIMD * HID;
    const ushort* gB0 = wB + (size_t)(colbase + 16 * (2 * wave)     + l15) * HID + quad * 8;
    const ushort* gB1 = wB + (size_t)(colbase + 16 * (2 * wave + 1) + l15) * HID + quad * 8;

    floatx4 acc[4][4];
#pragma unroll
    for (int i = 0; i < 4; i++)
#pragma unroll
        for (int j = 0; j < 4; j++) acc[i][j] = (floatx4){0.f, 0.f, 0.f, 0.f};

    ISSUE_SLAB(0);
    const int nIter = HID / 32;
    for (int it = 0; it < nIter; ++it) {
        int cur = it & 1;
        __syncthreads();            // drains prefetch for buf[cur]
        if (it + 1 < nIter) ISSUE_SLAB(cur ^ 1);

        const bf16x8* fA = reinterpret_cast<const bf16x8*>(ldsA[cur]);
        const bf16x8* fB = reinterpret_cast<const bf16x8*>(ldsB[cur]);
        bf16x8 a[4], b[4];
#pragma unroll
        for (int i = 0; i < 4; i++) a[i] = fA[(4 * wrow + i) * 64 + lane];
#pragma unroll
        for (int j = 0; j < 4; j++) b[j] = fB[(4 * wcol + j) * 64 + lane];
#pragma unroll
        for (int i = 0; i < 4; i++)
#pragma unroll
            for (int j = 0; j < 4; j++)
                acc[i][j] = __builtin_amdgcn_mfma_f32_16x16x32_bf16(a[i], b[j], acc[i][j], 0, 0, 0);
    }

    // epilogue: bias, gate-scale, atomic scatter to out
#pragma unroll
    for (int i = 0; i < 4; i++) {
#pragma unroll
        for (int r = 0; r < 4; r++) {
            int pr = row0 + 64 * wrow + 16 * i + quad * 4 + r;
            if (pr < cnt) {
                int tok = atok[base + pr];
                float g = agate[base + pr];
                float* orow = out + (size_t)tok * DIMD;
#pragma unroll
                for (int j = 0; j < 4; j++) {
                    int col = colbase + 64 * wcol + 16 * j + l15;
                    atomicAdd(&orow[col], g * (acc[i][j][r] + b2[e * DIMD + col]));
                }
            }
        }
    }
}

// ---------------------------------------------------------------------------
extern "C" void kernel_launch(void* const* d_in, const int* in_sizes, int n_in,
                              void* d_out, int out_size, void* d_ws, size_t ws_size,
                              hipStream_t stream) {
    const float* x  = (const float*)d_in[0];
    const float* rw = (const float*)d_in[1];
    const float* w1 = (const float*)d_in[2];
    const float* b1 = (const float*)d_in[3];
    const float* w2 = (const float*)d_in[4];
    const float* b2 = (const float*)d_in[5];
    float* out = (float*)d_out;

    char* ws = (char*)d_ws;
    int*   counts  = (int*)(ws + OFF_COUNTS);
    int*   offsets = (int*)(ws + OFF_OFFSETS);
    int*   cursors = (int*)(ws + OFF_CURSORS);
    int*   tileoff = (int*)(ws + OFF_TILEOFF);
    int*   topki   = (int*)(ws + OFF_TOPKI);
    float* topkg   = (float*)(ws + OFF_TOPKG);
    float* blkps   = (float*)(ws + OFF_BLKPS);
    int*   atok    = (int*)(ws + OFF_ATOK);
    float* agate   = (float*)(ws + OFF_AGATE);
    ushort* Xg     = (ushort*)(ws + OFF_XG);
    ushort* w1b    = (ushort*)(ws + OFF_W1B);
    ushort* w2b    = (ushort*)(ws + OFF_W2B);
    unsigned short* Hbuf = (unsigned short*)(ws + OFF_H);

    // zero main output (atomic-scatter target); aux written by finalize
    zero_out_kernel<<<2048, 256, 0, stream>>>((float4*)out, TOKS * DIMD / 4);

    // weight conversions (independent of routing)
    convert_w_kernel<<<4096, 256, 0, stream>>>((const float4*)w1, (ushort4*)w1b,
                                               NE * HID * DIMD / 4);
    convert_w_kernel<<<4096, 256, 0, stream>>>((const float4*)w2, (ushort4*)w2b,
                                               NE * DIMD * HID / 4);

    router_kernel<<<TOKS / 4, 256, 0, stream>>>(x, rw, topki, topkg, blkps);
    finalize_kernel<<<1, 256, 0, stream>>>(topki, blkps, counts, offsets, cursors,
                                           tileoff, out + (size_t)TOKS * DIMD);
    fill_kernel<<<TOKS / 64, 64, 0, stream>>>(topki, topkg, cursors, atok, agate);
    gather_x_kernel<<<TOKS * 2, 256, 0, stream>>>(x, atok, Xg);

    // worst-case 128-row tiles: sum_e ceil(cnt_e/128) <= 16384/128 + 7 = 135
    phase1_kernel<<<135 * (HID / 128), 256, 0, stream>>>(
        Xg, w1b, b1, counts, offsets, tileoff, Hbuf);
    phase2_kernel<<<135 * (DIMD / 128), 256, 0, stream>>>(
        Hbuf, w2b, b2, counts, offsets, tileoff, atok, agate, out);
}

// Round 4
// 634.311 us; speedup vs baseline: 1.1615x; 1.1615x over previous
//
#include <hip/hip_runtime.h>

// ============================================================================
// MoE block (top-2 of 8 experts), T=8192 tokens, d=1024, h=2048.
// R4: single-buffer MFMA K-loops (dbuf was neutral - m99/m100 confirmed);
// atomic-free phase2: writes packed per-assignment Y rows (bf16), combine
// kernel gathers Y via inverse-position map, adds gate-weighted b2, writes
// out once (no zero pass). Conversions merged into one kernel; finalize
// vectorized.
//
// ws layout (bytes):
//   0       counts[8] / 64 offsets[9] / 128 cursors[8] / 192 tileoff[9]
//   256     topk_idx[16384] int
//   65792   topk_gate[16384] float
//   131328  block_probsum[2048*8] float
//   196864  assign_token[16384] int
//   262400  assign_gate[16384] float
//   327936  posinv[16384] int            (token -> packed row, x2)
//   1 MB    Xg[(16384+128) x 1024] bf16   (33.8 MB)
//   +       w1b[8*2048*1024] bf16         (33.6 MB)
//   +       w2b[8*1024*2048] bf16         (33.6 MB)
//   +       Hbuf[(16384+128) x 2048] bf16 (67.6 MB)
//   +       Y[(16384+128) x 1024] bf16    (33.8 MB)   total ~204 MB
// ============================================================================

#define TOKS 8192
#define DIMD 1024
#define HID  2048
#define NE   8

#define OFF_COUNTS   0
#define OFF_OFFSETS  64
#define OFF_CURSORS  128
#define OFF_TILEOFF  192
#define OFF_TOPKI    256
#define OFF_TOPKG    (OFF_TOPKI + TOKS*2*4)
#define OFF_BLKPS    (OFF_TOPKG + TOKS*2*4)
#define OFF_ATOK     (OFF_BLKPS + 2048*NE*4)
#define OFF_AGATE    (OFF_ATOK + TOKS*2*4)
#define OFF_PINV     (OFF_AGATE + TOKS*2*4)
#define OFF_XG       (1u << 20)
#define XG_ROWS      (TOKS*2 + 128)
#define OFF_W1B      (OFF_XG  + (size_t)XG_ROWS * DIMD * 2)
#define OFF_W2B      (OFF_W1B + (size_t)NE * HID * DIMD * 2)
#define OFF_H        (OFF_W2B + (size_t)NE * DIMD * HID * 2)
#define OFF_Y        (OFF_H   + (size_t)XG_ROWS * HID * 2)

typedef __bf16 bf16x8 __attribute__((ext_vector_type(8)));
typedef float  floatx4 __attribute__((ext_vector_type(4)));

__device__ __forceinline__ float bf2f(unsigned short u) {
    return __uint_as_float(((unsigned)u) << 16);
}
__device__ __forceinline__ unsigned short f2bf(float f) {
    unsigned u = __float_as_uint(f);
    unsigned r = (u + 0x7FFFu + ((u >> 16) & 1u)) >> 16;
    return (unsigned short)r;
}

#define GLOBAL_AS(p) ((const __attribute__((address_space(1))) unsigned int*)(p))
#define LDS_AS(p)    ((__attribute__((address_space(3))) unsigned int*)(p))

// ---------------------------------------------------------------------------
// Both weight tensors -> bf16 in one pass.
__global__ void convert_w_kernel(const float4* __restrict__ w1,
                                 ushort4* __restrict__ w1b, int n1,
                                 const float4* __restrict__ w2,
                                 ushort4* __restrict__ w2b, int n2) {
    int i = blockIdx.x * blockDim.x + threadIdx.x;
    int stride = gridDim.x * blockDim.x;
    int ntot = n1 + n2;
    for (; i < ntot; i += stride) {
        float4 v; ushort4 o;
        if (i < n1) v = w1[i]; else v = w2[i - n1];
        o.x = f2bf(v.x); o.y = f2bf(v.y); o.z = f2bf(v.z); o.w = f2bf(v.w);
        if (i < n1) w1b[i] = o; else w2b[i - n1] = o;
    }
}

// ---------------------------------------------------------------------------
// One wave per token: logits = x[t] . rw[e], softmax over 8, top-2, gates.
__global__ __launch_bounds__(256) void router_kernel(
    const float* __restrict__ x, const float* __restrict__ rw,
    int* __restrict__ topki, float* __restrict__ topkg,
    float* __restrict__ blkps)
{
    int wave = threadIdx.x >> 6;
    int lane = threadIdx.x & 63;
    int t = blockIdx.x * 4 + wave;
    const float* xt = x + (size_t)t * DIMD;

    float acc[NE];
#pragma unroll
    for (int e = 0; e < NE; e++) acc[e] = 0.f;
    for (int i = 0; i < DIMD / 64; i++) {
        float xv = xt[lane + 64 * i];
#pragma unroll
        for (int e = 0; e < NE; e++) acc[e] += xv * rw[e * DIMD + lane + 64 * i];
    }
#pragma unroll
    for (int off = 32; off > 0; off >>= 1) {
#pragma unroll
        for (int e = 0; e < NE; e++) acc[e] += __shfl_down(acc[e], off);
    }

    __shared__ float ps[4][NE];
    if (lane == 0) {
        float m = acc[0];
#pragma unroll
        for (int e = 1; e < NE; e++) m = fmaxf(m, acc[e]);
        float ex[NE], s = 0.f;
#pragma unroll
        for (int e = 0; e < NE; e++) { ex[e] = expf(acc[e] - m); s += ex[e]; }
        float inv = 1.f / s;
#pragma unroll
        for (int e = 0; e < NE; e++) ps[wave][e] = ex[e] * inv;

        int i0 = 0; float l0 = acc[0];
#pragma unroll
        for (int e = 1; e < NE; e++) if (acc[e] > l0) { l0 = acc[e]; i0 = e; }
        int i1 = -1; float l1 = -3.4e38f;
#pragma unroll
        for (int e = 0; e < NE; e++) if (e != i0 && acc[e] > l1) { l1 = acc[e]; i1 = e; }
        float e1 = expf(l1 - l0);
        float g0 = 1.f / (1.f + e1);
        float g1 = e1 * g0;
        topki[t * 2 + 0] = i0; topki[t * 2 + 1] = i1;
        topkg[t * 2 + 0] = g0; topkg[t * 2 + 1] = g1;
    }
    __syncthreads();
    if (threadIdx.x < NE) {
        float s = ps[0][threadIdx.x] + ps[1][threadIdx.x] + ps[2][threadIdx.x] + ps[3][threadIdx.x];
        blkps[blockIdx.x * NE + threadIdx.x] = s;
    }
}

// ---------------------------------------------------------------------------
// Single block: counts, offsets (packed row bases), cursors, 128-row tile
// prefix, aux loss. Vectorized int4/float4 reads.
__global__ __launch_bounds__(256) void finalize_kernel(
    const int* __restrict__ topki, const float* __restrict__ blkps,
    int* __restrict__ counts, int* __restrict__ offsets, int* __restrict__ cursors,
    int* __restrict__ tileoff, float* __restrict__ aux_out)
{
    __shared__ float psum[NE];
    __shared__ int cnt[NE];
    int tid = threadIdx.x;
    if (tid < NE) { psum[tid] = 0.f; cnt[tid] = 0; }
    __syncthreads();

    float lp[NE]; int lc[NE];
#pragma unroll
    for (int e = 0; e < NE; e++) { lp[e] = 0.f; lc[e] = 0; }
    const float4* bp4 = (const float4*)blkps;
    for (int i = tid; i < 2048 * NE / 4; i += 256) {
        float4 v = bp4[i];
        int eb = (4 * i) & 7;   // 0 or 4
        lp[eb + 0] += v.x; lp[eb + 1] += v.y; lp[eb + 2] += v.z; lp[eb + 3] += v.w;
    }
    const int4* ti4 = (const int4*)topki;
    for (int i = tid; i < TOKS * 2 / 4; i += 256) {
        int4 v = ti4[i];
        lc[v.x]++; lc[v.y]++; lc[v.z]++; lc[v.w]++;
    }
#pragma unroll
    for (int e = 0; e < NE; e++) { atomicAdd(&psum[e], lp[e]); atomicAdd(&cnt[e], lc[e]); }
    __syncthreads();

    if (tid == 0) {
        int off = 0, to = 0;
        for (int e = 0; e < NE; e++) {
            counts[e] = cnt[e];
            offsets[e] = off; cursors[e] = off;
            tileoff[e] = to;
            off += cnt[e];
            to += (cnt[e] + 127) >> 7;
        }
        offsets[NE] = off; tileoff[NE] = to;
        float aux = 0.f;
        for (int e = 0; e < NE; e++)
            aux += ((float)cnt[e] / (float)(TOKS * 2)) * (psum[e] / (float)TOKS);
        aux_out[0] = (float)NE * aux;
    }
}

// ---------------------------------------------------------------------------
// Build packed per-expert (token, gate) lists + inverse map token->position.
__global__ __launch_bounds__(64) void fill_kernel(
    const int* __restrict__ topki, const float* __restrict__ topkg,
    int* __restrict__ cursors, int* __restrict__ atok, float* __restrict__ agate,
    int* __restrict__ posinv)
{
    int lane = threadIdx.x;
    int t = blockIdx.x * 64 + lane;
    unsigned long long below = (lane == 63) ? 0x7FFFFFFFFFFFFFFFull
                                            : ((1ull << lane) - 1ull);
#pragma unroll
    for (int k = 0; k < 2; k++) {
        int e = topki[t * 2 + k];
        float g = topkg[t * 2 + k];
        for (int ee = 0; ee < NE; ee++) {
            bool pred = (e == ee);
            unsigned long long mask = __ballot(pred ? 1 : 0);
            if (mask) {
                int leader = __ffsll((unsigned long long)mask) - 1;
                int base = 0;
                if (lane == leader) base = atomicAdd(&cursors[ee], (int)__popcll(mask));
                base = __shfl(base, leader);
                if (pred) {
                    int pos = base + (int)__popcll(mask & below);
                    atok[pos] = t;
                    agate[pos] = g;
                    posinv[t * 2 + k] = pos;
                }
            }
        }
    }
}

// ---------------------------------------------------------------------------
// Gather x rows into packed assignment order, fp32 -> bf16.
__global__ __launch_bounds__(256) void gather_x_kernel(
    const float* __restrict__ x, const int* __restrict__ atok,
    ushort* __restrict__ Xg)
{
    int r = blockIdx.x;
    int tid = threadIdx.x;
    int tok = atok[r];
    float4 v = ((const float4*)(x + (size_t)tok * DIMD))[tid];
    ushort4 o;
    o.x = f2bf(v.x); o.y = f2bf(v.y); o.z = f2bf(v.z); o.w = f2bf(v.w);
    ((ushort4*)(Xg + (size_t)r * DIMD))[tid] = o;
}

// ---------------------------------------------------------------------------
// MFMA GEMM phase 1: H[r,:] = gelu(Xg[r,:] @ w1b[e]^T + b1[e]) (bf16 out).
// 128x128 tile, BK=32, 4 waves, global_load_lds width=16, single-buffered.
__global__ __launch_bounds__(256) void phase1_kernel(
    const ushort* __restrict__ Xg, const ushort* __restrict__ w1b,
    const float* __restrict__ b1,
    const int* __restrict__ counts, const int* __restrict__ offsets,
    const int* __restrict__ tileoff, unsigned short* __restrict__ Hbuf)
{
    const int NCOLT = HID / 128;   // 16
    int total = tileoff[NE] * NCOLT;
    int idx = blockIdx.x;
    if (idx >= total) return;
    int ct = idx & (NCOLT - 1);
    int rowt = idx / NCOLT;
    int e = 0;
    while (rowt >= tileoff[e + 1]) e++;
    int row0 = (rowt - tileoff[e]) * 128;
    int cnt = counts[e];
    int base = offsets[e];
    int colbase = ct * 128;

    __shared__ ushort ldsA[128 * 32];
    __shared__ ushort ldsB[128 * 32];

    int tid = threadIdx.x;
    int lane = tid & 63;
    int wave = tid >> 6;
    int wrow = wave >> 1, wcol = wave & 1;
    int l15 = lane & 15, quad = lane >> 4;

    const ushort* gA0 = Xg + (size_t)(base + row0 + 16 * (2 * wave)     + l15) * DIMD + quad * 8;
    const ushort* gA1 = Xg + (size_t)(base + row0 + 16 * (2 * wave + 1) + l15) * DIMD + quad * 8;
    const ushort* wB  = w1b + (size_t)e * HID * DIMD;
    const ushort* gB0 = wB + (size_t)(colbase + 16 * (2 * wave)     + l15) * DIMD + quad * 8;
    const ushort* gB1 = wB + (size_t)(colbase + 16 * (2 * wave + 1) + l15) * DIMD + quad * 8;

    ushort* ldA0 = &ldsA[(2 * wave) * 512];
    ushort* ldA1 = &ldsA[(2 * wave + 1) * 512];
    ushort* ldB0 = &ldsB[(2 * wave) * 512];
    ushort* ldB1 = &ldsB[(2 * wave + 1) * 512];

    floatx4 acc[4][4];
#pragma unroll
    for (int i = 0; i < 4; i++)
#pragma unroll
        for (int j = 0; j < 4; j++) acc[i][j] = (floatx4){0.f, 0.f, 0.f, 0.f};

    const bf16x8* fA = reinterpret_cast<const bf16x8*>(ldsA);
    const bf16x8* fB = reinterpret_cast<const bf16x8*>(ldsB);

    for (int k0 = 0; k0 < DIMD; k0 += 32) {
        __syncthreads();
        __builtin_amdgcn_global_load_lds(GLOBAL_AS(gA0), LDS_AS(ldA0), 16, 0, 0);
        __builtin_amdgcn_global_load_lds(GLOBAL_AS(gA1), LDS_AS(ldA1), 16, 0, 0);
        __builtin_amdgcn_global_load_lds(GLOBAL_AS(gB0), LDS_AS(ldB0), 16, 0, 0);
        __builtin_amdgcn_global_load_lds(GLOBAL_AS(gB1), LDS_AS(ldB1), 16, 0, 0);
        gA0 += 32; gA1 += 32; gB0 += 32; gB1 += 32;
        __syncthreads();

        bf16x8 a[4], b[4];
#pragma unroll
        for (int i = 0; i < 4; i++) a[i] = fA[(4 * wrow + i) * 64 + lane];
#pragma unroll
        for (int j = 0; j < 4; j++) b[j] = fB[(4 * wcol + j) * 64 + lane];
#pragma unroll
        for (int i = 0; i < 4; i++)
#pragma unroll
            for (int j = 0; j < 4; j++)
                acc[i][j] = __builtin_amdgcn_mfma_f32_16x16x32_bf16(a[i], b[j], acc[i][j], 0, 0, 0);
    }

    // epilogue: bias + exact GELU, bf16 store. C/D: col=lane&15, row=quad*4+reg
#pragma unroll
    for (int i = 0; i < 4; i++) {
#pragma unroll
        for (int r = 0; r < 4; r++) {
            int pr = row0 + 64 * wrow + 16 * i + quad * 4 + r;
            if (pr < cnt) {
                size_t hrow = (size_t)(base + pr) * HID;
#pragma unroll
                for (int j = 0; j < 4; j++) {
                    int col = colbase + 64 * wcol + 16 * j + l15;
                    float v = acc[i][j][r] + b1[e * HID + col];
                    v = 0.5f * v * (1.f + erff(v * 0.70710678118654752f));
                    Hbuf[hrow + col] = f2bf(v);
                }
            }
        }
    }
}

// ---------------------------------------------------------------------------
// MFMA GEMM phase 2: Y[r,:] = H[r,:] @ w2b[e]^T (no bias, no gate), bf16 out.
__global__ __launch_bounds__(256) void phase2_kernel(
    const ushort* __restrict__ Hbuf, const ushort* __restrict__ w2b,
    const int* __restrict__ counts, const int* __restrict__ offsets,
    const int* __restrict__ tileoff, ushort* __restrict__ Y)
{
    const int NCOLT = DIMD / 128;  // 8
    int total = tileoff[NE] * NCOLT;
    int idx = blockIdx.x;
    if (idx >= total) return;
    int ct = idx & (NCOLT - 1);
    int rowt = idx / NCOLT;
    int e = 0;
    while (rowt >= tileoff[e + 1]) e++;
    int row0 = (rowt - tileoff[e]) * 128;
    int cnt = counts[e];
    int base = offsets[e];
    int colbase = ct * 128;

    __shared__ ushort ldsA[128 * 32];
    __shared__ ushort ldsB[128 * 32];

    int tid = threadIdx.x;
    int lane = tid & 63;
    int wave = tid >> 6;
    int wrow = wave >> 1, wcol = wave & 1;
    int l15 = lane & 15, quad = lane >> 4;

    const ushort* gA0 = Hbuf + (size_t)(base + row0 + 16 * (2 * wave)     + l15) * HID + quad * 8;
    const ushort* gA1 = Hbuf + (size_t)(base + row0 + 16 * (2 * wave + 1) + l15) * HID + quad * 8;
    const ushort* wB  = w2b + (size_t)e * DIMD * HID;
    const ushort* gB0 = wB + (size_t)(colbase + 16 * (2 * wave)     + l15) * HID + quad * 8;
    const ushort* gB1 = wB + (size_t)(colbase + 16 * (2 * wave + 1) + l15) * HID + quad * 8;

    ushort* ldA0 = &ldsA[(2 * wave) * 512];
    ushort* ldA1 = &ldsA[(2 * wave + 1) * 512];
    ushort* ldB0 = &ldsB[(2 * wave) * 512];
    ushort* ldB1 = &ldsB[(2 * wave + 1) * 512];

    floatx4 acc[4][4];
#pragma unroll
    for (int i = 0; i < 4; i++)
#pragma unroll
        for (int j = 0; j < 4; j++) acc[i][j] = (floatx4){0.f, 0.f, 0.f, 0.f};

    const bf16x8* fA = reinterpret_cast<const bf16x8*>(ldsA);
    const bf16x8* fB = reinterpret_cast<const bf16x8*>(ldsB);

    for (int k0 = 0; k0 < HID; k0 += 32) {
        __syncthreads();
        __builtin_amdgcn_global_load_lds(GLOBAL_AS(gA0), LDS_AS(ldA0), 16, 0, 0);
        __builtin_amdgcn_global_load_lds(GLOBAL_AS(gA1), LDS_AS(ldA1), 16, 0, 0);
        __builtin_amdgcn_global_load_lds(GLOBAL_AS(gB0), LDS_AS(ldB0), 16, 0, 0);
        __builtin_amdgcn_global_load_lds(GLOBAL_AS(gB1), LDS_AS(ldB1), 16, 0, 0);
        gA0 += 32; gA1 += 32; gB0 += 32; gB1 += 32;
        __syncthreads();

        bf16x8 a[4], b[4];
#pragma unroll
        for (int i = 0; i < 4; i++) a[i] = fA[(4 * wrow + i) * 64 + lane];
#pragma unroll
        for (int j = 0; j < 4; j++) b[j] = fB[(4 * wcol + j) * 64 + lane];
#pragma unroll
        for (int i = 0; i < 4; i++)
#pragma unroll
            for (int j = 0; j < 4; j++)
                acc[i][j] = __builtin_amdgcn_mfma_f32_16x16x32_bf16(a[i], b[j], acc[i][j], 0, 0, 0);
    }

    // epilogue: plain bf16 store of raw GEMM rows (bias+gate applied in combine)
#pragma unroll
    for (int i = 0; i < 4; i++) {
#pragma unroll
        for (int r = 0; r < 4; r++) {
            int pr = row0 + 64 * wrow + 16 * i + quad * 4 + r;
            if (pr < cnt) {
                size_t yrow = (size_t)(base + pr) * DIMD;
#pragma unroll
                for (int j = 0; j < 4; j++) {
                    int col = colbase + 64 * wcol + 16 * j + l15;
                    Y[yrow + col] = f2bf(acc[i][j][r]);
                }
            }
        }
    }
}

// ---------------------------------------------------------------------------
// Combine: out[t,:] = g0*Y[p0,:] + g1*Y[p1,:] + g0*b2[e0,:] + g1*b2[e1,:].
// One wave per token (4 tokens/block); lane covers 4 cols via ushort4.
__global__ __launch_bounds__(256) void combine_kernel(
    const ushort* __restrict__ Y, const float* __restrict__ b2,
    const int* __restrict__ topki, const float* __restrict__ topkg,
    const int* __restrict__ posinv, float* __restrict__ out)
{
    int wave = threadIdx.x >> 6;
    int lane = threadIdx.x & 63;
    int t = blockIdx.x * 4 + wave;
    int e0 = topki[t * 2 + 0], e1 = topki[t * 2 + 1];
    float g0 = topkg[t * 2 + 0], g1 = topkg[t * 2 + 1];
    int p0 = posinv[t * 2 + 0], p1 = posinv[t * 2 + 1];

    const ushort4* y0 = (const ushort4*)(Y + (size_t)p0 * DIMD);
    const ushort4* y1 = (const ushort4*)(Y + (size_t)p1 * DIMD);
    const float4* b20 = (const float4*)(b2 + (size_t)e0 * DIMD);
    const float4* b21 = (const float4*)(b2 + (size_t)e1 * DIMD);
    float4* o4 = (float4*)(out + (size_t)t * DIMD);

#pragma unroll
    for (int c = 0; c < DIMD / 4 / 64; c++) {   // 4 iterations
        int i = lane + 64 * c;
        ushort4 a = y0[i], b = y1[i];
        float4 ba = b20[i], bb = b21[i];
        float4 r;
        r.x = g0 * (bf2f(a.x) + ba.x) + g1 * (bf2f(b.x) + bb.x);
        r.y = g0 * (bf2f(a.y) + ba.y) + g1 * (bf2f(b.y) + bb.y);
        r.z = g0 * (bf2f(a.z) + ba.z) + g1 * (bf2f(b.z) + bb.z);
        r.w = g0 * (bf2f(a.w) + ba.w) + g1 * (bf2f(b.w) + bb.w);
        o4[i] = r;
    }
}

// ---------------------------------------------------------------------------
extern "C" void kernel_launch(void* const* d_in, const int* in_sizes, int n_in,
                              void* d_out, int out_size, void* d_ws, size_t ws_size,
                              hipStream_t stream) {
    const float* x  = (const float*)d_in[0];
    const float* rw = (const float*)d_in[1];
    const float* w1 = (const float*)d_in[2];
    const float* b1 = (const float*)d_in[3];
    const float* w2 = (const float*)d_in[4];
    const float* b2 = (const float*)d_in[5];
    float* out = (float*)d_out;

    char* ws = (char*)d_ws;
    int*   counts  = (int*)(ws + OFF_COUNTS);
    int*   offsets = (int*)(ws + OFF_OFFSETS);
    int*   cursors = (int*)(ws + OFF_CURSORS);
    int*   tileoff = (int*)(ws + OFF_TILEOFF);
    int*   topki   = (int*)(ws + OFF_TOPKI);
    float* topkg   = (float*)(ws + OFF_TOPKG);
    float* blkps   = (float*)(ws + OFF_BLKPS);
    int*   atok    = (int*)(ws + OFF_ATOK);
    float* agate   = (float*)(ws + OFF_AGATE);
    int*   posinv  = (int*)(ws + OFF_PINV);
    ushort* Xg     = (ushort*)(ws + OFF_XG);
    ushort* w1b    = (ushort*)(ws + OFF_W1B);
    ushort* w2b    = (ushort*)(ws + OFF_W2B);
    ushort* Hbuf   = (ushort*)(ws + OFF_H);
    ushort* Y      = (ushort*)(ws + OFF_Y);

    // weight conversions (independent of routing), one pass
    convert_w_kernel<<<8192, 256, 0, stream>>>(
        (const float4*)w1, (ushort4*)w1b, NE * HID * DIMD / 4,
        (const float4*)w2, (ushort4*)w2b, NE * DIMD * HID / 4);

    router_kernel<<<TOKS / 4, 256, 0, stream>>>(x, rw, topki, topkg, blkps);
    finalize_kernel<<<1, 256, 0, stream>>>(topki, blkps, counts, offsets, cursors,
                                           tileoff, out + (size_t)TOKS * DIMD);
    fill_kernel<<<TOKS / 64, 64, 0, stream>>>(topki, topkg, cursors, atok, agate,
                                              posinv);
    gather_x_kernel<<<TOKS * 2, 256, 0, stream>>>(x, atok, Xg);

    // worst-case 128-row tiles: sum_e ceil(cnt_e/128) <= 16384/128 + 7 = 135
    phase1_kernel<<<135 * (HID / 128), 256, 0, stream>>>(
        Xg, w1b, b1, counts, offsets, tileoff, Hbuf);
    phase2_kernel<<<135 * (DIMD / 128), 256, 0, stream>>>(
        Hbuf, w2b, counts, offsets, tileoff, Y);
    combine_kernel<<<TOKS / 4, 256, 0, stream>>>(Y, b2, topki, topkg, posinv, out);
}